// Round 7
// baseline (469.713 us; speedup 1.0000x reference)
//
#include <hip/hip_runtime.h>
#include <hip/hip_bf16.h>

#define NN 50000
#define EE 800000
#define EP (EE + NN)            // edges + self loops (self loop = slot 0 of each node)

// NOTE: harness materializes integer inputs as int32 -> edge_index is const int*.

typedef short bf16x8 __attribute__((ext_vector_type(8)));
typedef float f32x4  __attribute__((ext_vector_type(4)));

__device__ __forceinline__ float bf2f(unsigned short u) {
    return __uint_as_float(((unsigned)u) << 16);
}
__device__ __forceinline__ unsigned short f2bf(float f) {
    unsigned b = __float_as_uint(f);
    b += 0x7fffu + ((b >> 16) & 1u);           // RNE
    return (unsigned short)(b >> 16);
}
// dword holding two bf16 -> two floats (1 shl + 1 and)
__device__ __forceinline__ float2 bfpair(unsigned u) {
    return make_float2(__uint_as_float(u << 16), __uint_as_float(u & 0xffff0000u));
}

// ---------------- fused prep: v + Wt casts + degree/attr-sum hist + x cast ----
// block 0: v ; [1,256]: Wt ; [257,3381]: hist+lsum ; [3382,9631]: castx
__global__ void k_prep(const float* __restrict__ We1, const float* __restrict__ ae1,
                       const float* __restrict__ We2, const float* __restrict__ ae2,
                       float* __restrict__ v,
                       const float* __restrict__ W1, unsigned short* __restrict__ W1t,
                       const float* __restrict__ W2, unsigned short* __restrict__ W2t,
                       const int* __restrict__ ei, const float* __restrict__ eattr,
                       int* __restrict__ idg, float* __restrict__ lsum,
                       const float* __restrict__ x, unsigned short* __restrict__ xb) {
    int bid = blockIdx.x, t = threadIdx.x;
    if (bid == 0) {
        if (t < 8) {            // layer1: c=t>>2, h=t&3 -> v[c*4+h]
            int c = t >> 2, h = t & 3;
            float s = 0.f;
            for (int d = 0; d < 64; d++) s += We1[c * 256 + h * 64 + d] * ae1[h * 64 + d];
            v[c * 4 + h] = s;
        } else if (t < 10) {    // layer2: c=t-8 -> v[8+c]
            int c = t - 8;
            float s = 0.f;
            for (int d = 0; d < 128; d++) s += We2[c * 128 + d] * ae2[d];
            v[8 + c] = s;
        }
    } else if (bid <= 256) {
        int idx = (bid - 1) * 256 + t;
        if (idx < 32768) {                 // W1: 128x256 -> 256x128
            int k = idx >> 8, n = idx & 255;
            W1t[n * 128 + k] = f2bf(W1[idx]);
        } else {                           // W2: 256x128 -> 128x256
            int i = idx - 32768;
            int k = i >> 7, n = i & 127;
            W2t[n * 256 + k] = f2bf(W2[i]);
        }
    } else if (bid <= 256 + 3125) {
        int e = (bid - 257) * 256 + t;
        if (e < EE) {
            int d = ei[EE + e];
            float2 a = ((const float2*)eattr)[e];
            atomicAdd(&idg[d], 1);
            atomicAdd(&lsum[2 * d],     a.x);
            atomicAdd(&lsum[2 * d + 1], a.y);
        }
    } else {
        int i = (bid - 3382) * 256 + t;
        if (i < NN * 128 / 4) {
            float4 vv = ((const float4*)x)[i];
            ushort4 o;
            o.x = f2bf(vv.x); o.y = f2bf(vv.y); o.z = f2bf(vv.z); o.w = f2bf(vv.w);
            ((ushort4*)xb)[i] = o;
        }
    }
}

// ---------------- single-block exclusive scan of (idg+1) -> rowptr ------------
#define CHUNK 49    // 1024*49 = 50176 >= NN
__global__ __launch_bounds__(1024) void k_scan(const int* __restrict__ idg,
                                               int* __restrict__ rowptr) {
    __shared__ int sh[1024];
    int t = threadIdx.x;
    int base = t * CHUNK;
    int loc[CHUNK];
    int s = 0;
    #pragma unroll
    for (int j = 0; j < CHUNK; j++) {
        int i = base + j;
        loc[j] = s;
        s += (i < NN) ? (idg[i] + 1) : 0;
    }
    sh[t] = s;
    __syncthreads();
    for (int off = 1; off < 1024; off <<= 1) {
        int a = (t >= off) ? sh[t - off] : 0;
        __syncthreads();
        sh[t] += a;
        __syncthreads();
    }
    int pre = sh[t] - s;        // exclusive prefix of this thread's chunk
    #pragma unroll
    for (int j = 0; j < CHUNK; j++) {
        int i = base + j;
        if (i < NN) rowptr[i] = pre + loc[j];
    }
    if (t == 1023) rowptr[NN] = sh[1023];    // == EP
}

// ---------------- scatter edges + fill self-loop slots ------------------------
// blocks [0,3125): real edges -> slots [rowptr[d]+1, rowptr[d+1])
// blocks [3125,3321): self slot 0 per node: {n, mean attrs}
__global__ void k_scatter(const int* __restrict__ ei, const float* __restrict__ eattr,
                          const int* __restrict__ rowptr, int* __restrict__ cnt,
                          const int* __restrict__ idg, const float* __restrict__ lsum,
                          int2* __restrict__ slot) {
    int bid = blockIdx.x, t = threadIdx.x;
    if (bid < 3125) {
        int e = bid * 256 + t;
        if (e >= EE) return;
        int s = ei[e], d = ei[EE + e];
        int p = rowptr[d] + 1 + atomicAdd(&cnt[d], 1);
        float2 a = ((const float2*)eattr)[e];
        unsigned a0 = f2bf(a.x), a1 = f2bf(a.y);
        slot[p] = make_int2(s, (int)(a0 | (a1 << 16)));
    } else {
        int n = (bid - 3125) * 256 + t;
        if (n >= NN) return;
        float dg = fmaxf((float)idg[n], 1.0f);
        unsigned b0 = f2bf(lsum[2 * n] / dg), b1v = f2bf(lsum[2 * n + 1] / dg);
        slot[rowptr[n]] = make_int2(n, (int)(b0 | (b1v << 16)));
    }
}

// ---------------- MFMA bf16 GEMM with fused attention-scalar epilogue ---------
// C[M,N] = A[M,K] @ Bt[N,K]^T (bf16 out). Per block: 128 rows x NT*16 cols.
template <int K, int NT, int H>
__global__ __launch_bounds__(256) void gemm_mfma(const unsigned short* __restrict__ A,
                                                 const unsigned short* __restrict__ Bt,
                                                 unsigned short* __restrict__ C,
                                                 const float* __restrict__ avs,
                                                 const float* __restrict__ avd,
                                                 float* __restrict__ asrc,
                                                 float* __restrict__ adst,
                                                 int M, int N) {
    int wave = threadIdx.x >> 6, lane = threadIdx.x & 63;
    int l16 = lane & 15, quad = lane >> 4;
    int m0 = blockIdx.y * 128 + wave * 32;
    int n0 = blockIdx.x * (NT * 16);

    f32x4 acc[2][NT];
    #pragma unroll
    for (int mt = 0; mt < 2; mt++)
        #pragma unroll
        for (int nt = 0; nt < NT; nt++)
            acc[mt][nt] = (f32x4){0.f, 0.f, 0.f, 0.f};

    int ar0 = min(m0 + l16, M - 1);
    int ar1 = min(m0 + 16 + l16, M - 1);
    const unsigned short* a0 = A + (size_t)ar0 * K + quad * 8;
    const unsigned short* a1 = A + (size_t)ar1 * K + quad * 8;
    const unsigned short* bp = Bt + (size_t)(n0 + l16) * K + quad * 8;

    #pragma unroll
    for (int k0 = 0; k0 < K; k0 += 32) {
        bf16x8 af0 = *(const bf16x8*)(a0 + k0);
        bf16x8 af1 = *(const bf16x8*)(a1 + k0);
        #pragma unroll
        for (int nt = 0; nt < NT; nt++) {
            bf16x8 bf = *(const bf16x8*)(bp + (size_t)nt * 16 * K + k0);
            acc[0][nt] = __builtin_amdgcn_mfma_f32_16x16x32_bf16(af0, bf, acc[0][nt], 0, 0, 0);
            acc[1][nt] = __builtin_amdgcn_mfma_f32_16x16x32_bf16(af1, bf, acc[1][nt], 0, 0, 0);
        }
    }

    // C store. C/D layout: col = l16, row = quad*4 + reg
    #pragma unroll
    for (int mt = 0; mt < 2; mt++)
        #pragma unroll
        for (int reg = 0; reg < 4; reg++) {
            int row = m0 + mt * 16 + quad * 4 + reg;
            if (row < M) {
                #pragma unroll
                for (int nt = 0; nt < NT; nt++)
                    C[(size_t)row * N + n0 + nt * 16 + l16] = f2bf(acc[mt][nt][reg]);
            }
        }

    // fused attn scalars: asrc/adst[row, head] from fp32 acc
    float ws[NT], wd[NT];
    #pragma unroll
    for (int nt = 0; nt < NT; nt++) {
        ws[nt] = avs[n0 + nt * 16 + l16];
        wd[nt] = avd[n0 + nt * 16 + l16];
    }
    int hh = n0 >> 6;          // head index (layer1: blockIdx.x; layer2: 0)
    #pragma unroll
    for (int mt = 0; mt < 2; mt++)
        #pragma unroll
        for (int reg = 0; reg < 4; reg++) {
            int row = m0 + mt * 16 + quad * 4 + reg;
            float s1 = 0.f, s2 = 0.f;
            #pragma unroll
            for (int nt = 0; nt < NT; nt++) {
                float c = acc[mt][nt][reg];
                s1 += c * ws[nt];
                s2 += c * wd[nt];
            }
            #pragma unroll
            for (int off = 1; off < 16; off <<= 1) {
                s1 += __shfl_xor(s1, off);
                s2 += __shfl_xor(s2, off);
            }
            if (l16 == 0 && row < M) {
                asrc[row * H + hh] = s1;
                adst[row * H + hh] = s2;
            }
        }
}

// ---------------- layer1 fused softmax+aggregate+bias+ELU ---------------------
// one wave / node; alpha prefetch: lane = (edge j = lane&15, head = lane>>4);
// gather: half-wave per edge, 16B (8 bf16 ch) per lane; packed f32-pair FMAs.
__global__ __launch_bounds__(256) void k_agg1(const int* __restrict__ rowptr,
                       const int2* __restrict__ slot, const float* __restrict__ asrc,
                       const float* __restrict__ adst, const float* __restrict__ v,
                       const unsigned short* __restrict__ hb, const float* __restrict__ b1,
                       unsigned short* __restrict__ h2b) {
    int node = blockIdx.x * 4 + (threadIdx.x >> 6);
    if (node >= NN) return;
    int lane = threadIdx.x & 63;
    int j    = lane & 15;        // prefetch: edge within batch
    int hp   = lane >> 4;        // prefetch: head
    int half = lane >> 5;        // gather: which edge of the pair
    int hl   = lane & 31;        // gather: channel-lane (8 ch each)
    int hh2  = hl >> 3;          // head owning this lane's channels
    int beg = rowptr[node], end = rowptr[node + 1];
    float ad_p = adst[node * 4 + hp];
    float v0 = v[hp], v1 = v[4 + hp];
    float2 acc2[4] = {};
    float den = 0.f;
    for (int pb = beg; pb < end; pb += 16) {
        int m = min(16, end - pb);
        int sj = 0; float exv = 0.f;
        if (j < m) {
            int2 sl = slot[pb + j];
            sj = sl.x;
            unsigned au = (unsigned)sl.y;
            float2 a = bfpair(au);     // a.x = attr0<<16 form, a.y = attr1 masked form
            float al = asrc[sj * 4 + hp] + ad_p + a.x * v0 + a.y * v1;
            al = (al > 0.f) ? al : 0.2f * al;
            exv = __expf(al);
        }
        den += exv;
        #pragma unroll 2
        for (int j2 = 0; j2 < m; j2 += 2) {
            int jj = j2 + half;                      // may hit m (odd m): w=0
            int s   = __shfl(sj, jj);
            float w = __shfl(exv, jj + (hh2 << 4));
            uint4 raw = *(const uint4*)(hb + (size_t)s * 256 + hl * 8);
            float2 p0 = bfpair(raw.x), p1 = bfpair(raw.y);
            float2 p2 = bfpair(raw.z), p3 = bfpair(raw.w);
            acc2[0].x += w * p0.x; acc2[0].y += w * p0.y;
            acc2[1].x += w * p1.x; acc2[1].y += w * p1.y;
            acc2[2].x += w * p2.x; acc2[2].y += w * p2.y;
            acc2[3].x += w * p3.x; acc2[3].y += w * p3.y;
        }
    }
    #pragma unroll
    for (int k = 0; k < 4; k++) {
        acc2[k].x += __shfl_down(acc2[k].x, 32);
        acc2[k].y += __shfl_down(acc2[k].y, 32);
    }
    #pragma unroll
    for (int off = 8; off; off >>= 1) den += __shfl_xor(den, off);
    float den_h = __shfl(den, hh2 << 4);
    if (lane < 32) {
        float inv = 1.f / (den_h + 1e-16f);
        short ov[8];
        #pragma unroll
        for (int k = 0; k < 4; k++) {
            float va = acc2[k].x * inv + b1[hl * 8 + 2 * k];
            float vb = acc2[k].y * inv + b1[hl * 8 + 2 * k + 1];
            va = (va > 0.f) ? va : __expf(va) - 1.f;
            vb = (vb > 0.f) ? vb : __expf(vb) - 1.f;
            ov[2 * k]     = (short)f2bf(va);
            ov[2 * k + 1] = (short)f2bf(vb);
        }
        bf16x8 o = {ov[0], ov[1], ov[2], ov[3], ov[4], ov[5], ov[6], ov[7]};
        *(bf16x8*)(h2b + (size_t)node * 256 + hl * 8) = o;
    }
}

// ---------------- layer2 fused softmax+aggregate+bias (H=1, 128ch, fp32 out) --
__global__ __launch_bounds__(256) void k_agg2(const int* __restrict__ rowptr,
                       const int2* __restrict__ slot, const float* __restrict__ asrc,
                       const float* __restrict__ adst, const float* __restrict__ v,
                       const unsigned short* __restrict__ gb, const float* __restrict__ b2,
                       float* __restrict__ outp) {
    int node = blockIdx.x * 4 + (threadIdx.x >> 6);
    if (node >= NN) return;
    int lane = threadIdx.x & 63;
    int q  = lane >> 4;          // gather: which edge of the quad
    int ql = lane & 15;          // gather: channel-lane (8 ch each)
    int beg = rowptr[node], end = rowptr[node + 1];
    float ad = adst[node];
    float v0 = v[0], v1 = v[1];
    float2 acc2[4] = {};
    float den = 0.f;
    for (int pb = beg; pb < end; pb += 64) {
        int m = min(64, end - pb);
        int sj = 0; float exv = 0.f;
        if (lane < m) {
            int2 sl = slot[pb + lane];
            sj = sl.x;
            float2 a = bfpair((unsigned)sl.y);
            float al = asrc[sj] + ad + a.x * v0 + a.y * v1;
            al = (al > 0.f) ? al : 0.2f * al;
            exv = __expf(al);
        }
        den += exv;
        #pragma unroll 2
        for (int j2 = 0; j2 < m; j2 += 4) {
            int jj = j2 + q;                         // may exceed m-1: w=0
            int s   = __shfl(sj, jj);
            float w = __shfl(exv, jj);
            uint4 raw = *(const uint4*)(gb + (size_t)s * 128 + ql * 8);
            float2 p0 = bfpair(raw.x), p1 = bfpair(raw.y);
            float2 p2 = bfpair(raw.z), p3 = bfpair(raw.w);
            acc2[0].x += w * p0.x; acc2[0].y += w * p0.y;
            acc2[1].x += w * p1.x; acc2[1].y += w * p1.y;
            acc2[2].x += w * p2.x; acc2[2].y += w * p2.y;
            acc2[3].x += w * p3.x; acc2[3].y += w * p3.y;
        }
    }
    #pragma unroll
    for (int k = 0; k < 4; k++) {
        acc2[k].x += __shfl_down(acc2[k].x, 32);
        acc2[k].y += __shfl_down(acc2[k].y, 32);
        acc2[k].x += __shfl_down(acc2[k].x, 16);
        acc2[k].y += __shfl_down(acc2[k].y, 16);
    }
    #pragma unroll
    for (int off = 32; off; off >>= 1) den += __shfl_xor(den, off);
    if (lane < 16) {
        float inv = 1.f / (den + 1e-16f);
        float4 o0, o1;
        o0.x = acc2[0].x * inv + b2[ql * 8 + 0];
        o0.y = acc2[0].y * inv + b2[ql * 8 + 1];
        o0.z = acc2[1].x * inv + b2[ql * 8 + 2];
        o0.w = acc2[1].y * inv + b2[ql * 8 + 3];
        o1.x = acc2[2].x * inv + b2[ql * 8 + 4];
        o1.y = acc2[2].y * inv + b2[ql * 8 + 5];
        o1.z = acc2[3].x * inv + b2[ql * 8 + 6];
        o1.w = acc2[3].y * inv + b2[ql * 8 + 7];
        *(float4*)(outp + (size_t)node * 128 + ql * 8)     = o0;
        *(float4*)(outp + (size_t)node * 128 + ql * 8 + 4) = o1;
    }
}

extern "C" void kernel_launch(void* const* d_in, const int* in_sizes, int n_in,
                              void* d_out, int out_size, void* d_ws, size_t ws_size,
                              hipStream_t stream) {
    const float* x     = (const float*)d_in[0];
    const int*   ei    = (const int*)d_in[1];      // int32 on device
    const float* eattr = (const float*)d_in[2];
    const float* W1    = (const float*)d_in[3];
    const float* We1   = (const float*)d_in[4];
    const float* as1   = (const float*)d_in[5];
    const float* ad1   = (const float*)d_in[6];
    const float* ae1   = (const float*)d_in[7];
    const float* b1    = (const float*)d_in[8];
    const float* W2    = (const float*)d_in[9];
    const float* We2   = (const float*)d_in[10];
    const float* as2   = (const float*)d_in[11];
    const float* ad2   = (const float*)d_in[12];
    const float* ae2   = (const float*)d_in[13];
    const float* b2    = (const float*)d_in[14];
    float* out = (float*)d_out;

    // ---- workspace carve ----
    int* idg    = (int*)d_ws;                      // NN
    int* cnt    = idg + NN;                        // NN
    float* lsum = (float*)(cnt + NN);              // 2*NN (zeroed with idg/cnt)
    int* rowptr = (int*)(lsum + 2 * NN);           // NN+16
    int2* slot  = (int2*)(rowptr + NN + 16);       // EP (8B-aligned)
    float* asrc1 = (float*)(slot + EP);            // 4*NN
    float* adst1 = asrc1 + 4 * NN;                 // 4*NN
    float* asrc2 = adst1 + 4 * NN;                 // NN
    float* adst2 = asrc2 + NN;                     // NN
    float* vbuf  = adst2 + NN;                     // 64
    unsigned short* ub = (unsigned short*)(((uintptr_t)(vbuf + 64) + 63) & ~(uintptr_t)63);
    unsigned short* x_bf  = ub;                      // NN*128
    unsigned short* W1t   = x_bf + (size_t)NN * 128; // 256*128
    unsigned short* W2t   = W1t + 32768;             // 128*256
    unsigned short* h1_bf = W2t + 32768;             // NN*256
    unsigned short* h2_bf = h1_bf + (size_t)NN * 256;// NN*256
    unsigned short* g2_bf = h2_bf + (size_t)NN * 256;// NN*128

    hipMemsetAsync(idg, 0, (size_t)4 * NN * sizeof(int), stream);   // idg+cnt+lsum

    // prep (v, Wt casts, hist+attr sums, x cast) + scan + scatter/selfslot
    k_prep<<<9632, 256, 0, stream>>>(We1, ae1, We2, ae2, vbuf, W1, W1t, W2, W2t,
                                     ei, eattr, idg, lsum, x, x_bf);
    k_scan<<<1, 1024, 0, stream>>>(idg, rowptr);
    k_scatter<<<3125 + (NN + 255) / 256, 256, 0, stream>>>(ei, eattr, rowptr, cnt,
                                                           idg, lsum, slot);

    // ---- layer 1 ----  (gemm with fused attn scalars)
    gemm_mfma<128, 4, 4><<<dim3(4, (NN + 127) / 128), 256, 0, stream>>>(
        x_bf, W1t, h1_bf, as1, ad1, asrc1, adst1, NN, 256);
    k_agg1<<<(NN + 3) / 4, 256, 0, stream>>>(rowptr, slot, asrc1, adst1, vbuf,
                                             h1_bf, b1, h2_bf);

    // ---- layer 2 ----
    gemm_mfma<256, 8, 1><<<dim3(1, (NN + 127) / 128), 256, 0, stream>>>(
        h2_bf, W2t, g2_bf, as2, ad2, asrc2, adst2, NN, 128);
    k_agg2<<<(NN + 3) / 4, 256, 0, stream>>>(rowptr, slot, asrc2, adst2, vbuf + 8,
                                             g2_bf, b2, out);
}

// Round 8
// 355.774 us; speedup vs baseline: 1.3203x; 1.3203x over previous
//
#include <hip/hip_runtime.h>
#include <hip/hip_bf16.h>

#define NN 50000
#define EE 800000
#define EP (EE + NN)            // edges + self loops (self loop = slot 0 of each node)
#define SCAN_B 2048
#define NB ((NN + SCAN_B - 1) / SCAN_B)   // 25 scan blocks

// NOTE: harness materializes integer inputs as int32 -> edge_index is const int*.
// NOTE (r7): fp32 scatter atomics for self-loop attr means cost ~80us (atomic-
// latency bound, VALUBusy<1%). Self-loop means are computed by re-reading the
// bucketed slots instead (k_selfattr).

typedef short bf16x8 __attribute__((ext_vector_type(8)));
typedef float f32x4  __attribute__((ext_vector_type(4)));

__device__ __forceinline__ float bf2f(unsigned short u) {
    return __uint_as_float(((unsigned)u) << 16);
}
__device__ __forceinline__ unsigned short f2bf(float f) {
    unsigned b = __float_as_uint(f);
    b += 0x7fffu + ((b >> 16) & 1u);           // RNE
    return (unsigned short)(b >> 16);
}
// dword holding two bf16 -> two floats (1 shl + 1 and)
__device__ __forceinline__ float2 bfpair(unsigned u) {
    return make_float2(__uint_as_float(u << 16), __uint_as_float(u & 0xffff0000u));
}

// ---------------- fused prep: v-projection + Wt casts + degree hist + x cast --
// block 0: v ; blocks [1,256]: Wt ; [257,3381]: hist ; [3382,9631]: castx
__global__ void k_prep(const float* __restrict__ We1, const float* __restrict__ ae1,
                       const float* __restrict__ We2, const float* __restrict__ ae2,
                       float* __restrict__ v,
                       const float* __restrict__ W1, unsigned short* __restrict__ W1t,
                       const float* __restrict__ W2, unsigned short* __restrict__ W2t,
                       const int* __restrict__ ei, int* __restrict__ idg,
                       const float* __restrict__ x, unsigned short* __restrict__ xb) {
    int bid = blockIdx.x, t = threadIdx.x;
    if (bid == 0) {
        if (t < 8) {            // layer1: c=t>>2, h=t&3 -> v[c*4+h]
            int c = t >> 2, h = t & 3;
            float s = 0.f;
            for (int d = 0; d < 64; d++) s += We1[c * 256 + h * 64 + d] * ae1[h * 64 + d];
            v[c * 4 + h] = s;
        } else if (t < 10) {    // layer2: c=t-8 -> v[8+c]
            int c = t - 8;
            float s = 0.f;
            for (int d = 0; d < 128; d++) s += We2[c * 128 + d] * ae2[d];
            v[8 + c] = s;
        }
    } else if (bid <= 256) {
        int idx = (bid - 1) * 256 + t;
        if (idx < 32768) {                 // W1: 128x256 -> 256x128
            int k = idx >> 8, n = idx & 255;
            W1t[n * 128 + k] = f2bf(W1[idx]);
        } else {                           // W2: 256x128 -> 128x256
            int i = idx - 32768;
            int k = i >> 7, n = i & 127;
            W2t[n * 256 + k] = f2bf(W2[i]);
        }
    } else if (bid <= 256 + 3125) {
        int e = (bid - 257) * 256 + t;
        if (e < EE) atomicAdd(&idg[ei[EE + e]], 1);
    } else {
        int i = (bid - 3382) * 256 + t;
        if (i < NN * 128 / 4) {
            float4 vv = ((const float4*)x)[i];
            ushort4 o;
            o.x = f2bf(vv.x); o.y = f2bf(vv.y); o.z = f2bf(vv.z); o.w = f2bf(vv.w);
            ((ushort4*)xb)[i] = o;
        }
    }
}

// ---------------- CSR build: 3-pass exclusive scan of (idg+1), then bucket ----
__global__ void k_scan1(const int* __restrict__ idg, int* __restrict__ rowptr,
                        int* __restrict__ bsum) {
    __shared__ int sh[512];
    int t = threadIdx.x;
    int base = blockIdx.x * SCAN_B + t * 4;
    int v[4]; int s = 0;
    #pragma unroll
    for (int j = 0; j < 4; j++) {
        int i = base + j;
        v[j] = (i < NN) ? (idg[i] + 1) : 0;   // +1 = self loop slot
        s += v[j];
    }
    sh[t] = s;
    __syncthreads();
    for (int off = 1; off < 512; off <<= 1) {
        int a = (t >= off) ? sh[t - off] : 0;
        __syncthreads();
        sh[t] += a;
        __syncthreads();
    }
    int run = sh[t] - s;
    #pragma unroll
    for (int j = 0; j < 4; j++) {
        int i = base + j;
        if (i < NN) rowptr[i] = run;
        run += v[j];
    }
    if (t == 511) bsum[blockIdx.x] = sh[511];
}

__global__ void k_scan2(const int* __restrict__ bsum, int* __restrict__ boff,
                        int* __restrict__ rowptr) {
    if (threadIdx.x == 0) {
        int acc = 0;
        for (int b = 0; b < NB; b++) { boff[b] = acc; acc += bsum[b]; }
        rowptr[NN] = acc;      // == EP
    }
}

__global__ void k_scan3(int* __restrict__ rowptr, const int* __restrict__ boff) {
    int t = threadIdx.x;
    int i = blockIdx.x * SCAN_B + t * 4;
    int off = boff[blockIdx.x];
    #pragma unroll
    for (int j = 0; j < 4; j++)
        if (i + j < NN) rowptr[i + j] += off;
}

// scatter real edges into slots [rowptr[d]+1, rowptr[d+1]); packed {src, bf16 attrs}
__global__ void k_scatter(const int* __restrict__ ei, const float* __restrict__ eattr,
                          const int* __restrict__ rowptr, int* __restrict__ cnt,
                          int2* __restrict__ slot) {
    int e = blockIdx.x * blockDim.x + threadIdx.x;
    if (e >= EE) return;
    int s = ei[e], d = ei[EE + e];
    int p = rowptr[d] + 1 + atomicAdd(&cnt[d], 1);
    float2 a = ((const float2*)eattr)[e];
    unsigned a0 = f2bf(a.x), a1 = f2bf(a.y);
    slot[p] = make_int2(s, (int)(a0 | (a1 << 16)));
}

// fill self-loop slot 0: src = node, attr = mean of incoming edge attrs
__global__ void k_selfattr(const int* __restrict__ rowptr, int2* __restrict__ slot) {
    int n = blockIdx.x * blockDim.x + threadIdx.x;
    if (n >= NN) return;
    int beg = rowptr[n], end = rowptr[n + 1];
    float s0 = 0.f, s1 = 0.f;
    for (int p = beg + 1; p < end; p++) {
        unsigned a = (unsigned)slot[p].y;
        s0 += bf2f((unsigned short)(a & 0xffff));
        s1 += bf2f((unsigned short)(a >> 16));
    }
    float dg = fmaxf((float)(end - beg - 1), 1.0f);
    unsigned b0 = f2bf(s0 / dg), b1v = f2bf(s1 / dg);
    slot[beg] = make_int2(n, (int)(b0 | (b1v << 16)));
}

// ---------------- MFMA bf16 GEMM with fused attention-scalar epilogue ---------
// C[M,N] = A[M,K] @ Bt[N,K]^T (bf16 out). Per block: 128 rows x NT*16 cols.
template <int K, int NT, int H>
__global__ __launch_bounds__(256) void gemm_mfma(const unsigned short* __restrict__ A,
                                                 const unsigned short* __restrict__ Bt,
                                                 unsigned short* __restrict__ C,
                                                 const float* __restrict__ avs,
                                                 const float* __restrict__ avd,
                                                 float* __restrict__ asrc,
                                                 float* __restrict__ adst,
                                                 int M, int N) {
    int wave = threadIdx.x >> 6, lane = threadIdx.x & 63;
    int l16 = lane & 15, quad = lane >> 4;
    int m0 = blockIdx.y * 128 + wave * 32;
    int n0 = blockIdx.x * (NT * 16);

    f32x4 acc[2][NT];
    #pragma unroll
    for (int mt = 0; mt < 2; mt++)
        #pragma unroll
        for (int nt = 0; nt < NT; nt++)
            acc[mt][nt] = (f32x4){0.f, 0.f, 0.f, 0.f};

    int ar0 = min(m0 + l16, M - 1);
    int ar1 = min(m0 + 16 + l16, M - 1);
    const unsigned short* a0 = A + (size_t)ar0 * K + quad * 8;
    const unsigned short* a1 = A + (size_t)ar1 * K + quad * 8;
    const unsigned short* bp = Bt + (size_t)(n0 + l16) * K + quad * 8;

    #pragma unroll
    for (int k0 = 0; k0 < K; k0 += 32) {
        bf16x8 af0 = *(const bf16x8*)(a0 + k0);
        bf16x8 af1 = *(const bf16x8*)(a1 + k0);
        #pragma unroll
        for (int nt = 0; nt < NT; nt++) {
            bf16x8 bf = *(const bf16x8*)(bp + (size_t)nt * 16 * K + k0);
            acc[0][nt] = __builtin_amdgcn_mfma_f32_16x16x32_bf16(af0, bf, acc[0][nt], 0, 0, 0);
            acc[1][nt] = __builtin_amdgcn_mfma_f32_16x16x32_bf16(af1, bf, acc[1][nt], 0, 0, 0);
        }
    }

    // C store. C/D layout: col = l16, row = quad*4 + reg
    #pragma unroll
    for (int mt = 0; mt < 2; mt++)
        #pragma unroll
        for (int reg = 0; reg < 4; reg++) {
            int row = m0 + mt * 16 + quad * 4 + reg;
            if (row < M) {
                #pragma unroll
                for (int nt = 0; nt < NT; nt++)
                    C[(size_t)row * N + n0 + nt * 16 + l16] = f2bf(acc[mt][nt][reg]);
            }
        }

    // fused attn scalars: asrc/adst[row, head] from fp32 acc
    float ws[NT], wd[NT];
    #pragma unroll
    for (int nt = 0; nt < NT; nt++) {
        ws[nt] = avs[n0 + nt * 16 + l16];
        wd[nt] = avd[n0 + nt * 16 + l16];
    }
    int hh = n0 >> 6;          // head index (layer1: blockIdx.x; layer2: 0)
    #pragma unroll
    for (int mt = 0; mt < 2; mt++)
        #pragma unroll
        for (int reg = 0; reg < 4; reg++) {
            int row = m0 + mt * 16 + quad * 4 + reg;
            float s1 = 0.f, s2 = 0.f;
            #pragma unroll
            for (int nt = 0; nt < NT; nt++) {
                float c = acc[mt][nt][reg];
                s1 += c * ws[nt];
                s2 += c * wd[nt];
            }
            #pragma unroll
            for (int off = 1; off < 16; off <<= 1) {
                s1 += __shfl_xor(s1, off);
                s2 += __shfl_xor(s2, off);
            }
            if (l16 == 0 && row < M) {
                asrc[row * H + hh] = s1;
                adst[row * H + hh] = s2;
            }
        }
}

// ---------------- layer1 fused softmax+aggregate+bias+ELU ---------------------
// one wave / node; alpha prefetch: lane = (edge j = lane&15, head = lane>>4);
// gather: half-wave per edge, 16B (8 bf16 ch) per lane; packed f32-pair FMAs.
__global__ __launch_bounds__(256) void k_agg1(const int* __restrict__ rowptr,
                       const int2* __restrict__ slot, const float* __restrict__ asrc,
                       const float* __restrict__ adst, const float* __restrict__ v,
                       const unsigned short* __restrict__ hb, const float* __restrict__ b1,
                       unsigned short* __restrict__ h2b) {
    int node = blockIdx.x * 4 + (threadIdx.x >> 6);
    if (node >= NN) return;
    int lane = threadIdx.x & 63;
    int j    = lane & 15;        // prefetch: edge within batch
    int hp   = lane >> 4;        // prefetch: head
    int half = lane >> 5;        // gather: which edge of the pair
    int hl   = lane & 31;        // gather: channel-lane (8 ch each)
    int hh2  = hl >> 3;          // head owning this lane's channels
    int beg = rowptr[node], end = rowptr[node + 1];
    float ad_p = adst[node * 4 + hp];
    float v0 = v[hp], v1 = v[4 + hp];
    float2 acc2[4] = {};
    float den = 0.f;
    for (int pb = beg; pb < end; pb += 16) {
        int m = min(16, end - pb);
        int sj = 0; float exv = 0.f;
        if (j < m) {
            int2 sl = slot[pb + j];
            sj = sl.x;
            float2 a = bfpair((unsigned)sl.y);
            float al = asrc[sj * 4 + hp] + ad_p + a.x * v0 + a.y * v1;
            al = (al > 0.f) ? al : 0.2f * al;
            exv = __expf(al);
        }
        den += exv;
        #pragma unroll 2
        for (int j2 = 0; j2 < m; j2 += 2) {
            int jj = j2 + half;                      // may hit m (odd m): w=0
            int s   = __shfl(sj, jj);
            float w = __shfl(exv, jj + (hh2 << 4));
            uint4 raw = *(const uint4*)(hb + (size_t)s * 256 + hl * 8);
            float2 p0 = bfpair(raw.x), p1 = bfpair(raw.y);
            float2 p2 = bfpair(raw.z), p3 = bfpair(raw.w);
            acc2[0].x += w * p0.x; acc2[0].y += w * p0.y;
            acc2[1].x += w * p1.x; acc2[1].y += w * p1.y;
            acc2[2].x += w * p2.x; acc2[2].y += w * p2.y;
            acc2[3].x += w * p3.x; acc2[3].y += w * p3.y;
        }
    }
    #pragma unroll
    for (int k = 0; k < 4; k++) {
        acc2[k].x += __shfl_down(acc2[k].x, 32);
        acc2[k].y += __shfl_down(acc2[k].y, 32);
    }
    #pragma unroll
    for (int off = 8; off; off >>= 1) den += __shfl_xor(den, off);
    float den_h = __shfl(den, hh2 << 4);
    if (lane < 32) {
        float inv = 1.f / (den_h + 1e-16f);
        short ov[8];
        #pragma unroll
        for (int k = 0; k < 4; k++) {
            float va = acc2[k].x * inv + b1[hl * 8 + 2 * k];
            float vb = acc2[k].y * inv + b1[hl * 8 + 2 * k + 1];
            va = (va > 0.f) ? va : __expf(va) - 1.f;
            vb = (vb > 0.f) ? vb : __expf(vb) - 1.f;
            ov[2 * k]     = (short)f2bf(va);
            ov[2 * k + 1] = (short)f2bf(vb);
        }
        bf16x8 o = {ov[0], ov[1], ov[2], ov[3], ov[4], ov[5], ov[6], ov[7]};
        *(bf16x8*)(h2b + (size_t)node * 256 + hl * 8) = o;
    }
}

// ---------------- layer2 fused softmax+aggregate+bias (H=1, 128ch, fp32 out) --
__global__ __launch_bounds__(256) void k_agg2(const int* __restrict__ rowptr,
                       const int2* __restrict__ slot, const float* __restrict__ asrc,
                       const float* __restrict__ adst, const float* __restrict__ v,
                       const unsigned short* __restrict__ gb, const float* __restrict__ b2,
                       float* __restrict__ outp) {
    int node = blockIdx.x * 4 + (threadIdx.x >> 6);
    if (node >= NN) return;
    int lane = threadIdx.x & 63;
    int q  = lane >> 4;          // gather: which edge of the quad
    int ql = lane & 15;          // gather: channel-lane (8 ch each)
    int beg = rowptr[node], end = rowptr[node + 1];
    float ad = adst[node];
    float v0 = v[0], v1 = v[1];
    float2 acc2[4] = {};
    float den = 0.f;
    for (int pb = beg; pb < end; pb += 64) {
        int m = min(64, end - pb);
        int sj = 0; float exv = 0.f;
        if (lane < m) {
            int2 sl = slot[pb + lane];
            sj = sl.x;
            float2 a = bfpair((unsigned)sl.y);
            float al = asrc[sj] + ad + a.x * v0 + a.y * v1;
            al = (al > 0.f) ? al : 0.2f * al;
            exv = __expf(al);
        }
        den += exv;
        #pragma unroll 2
        for (int j2 = 0; j2 < m; j2 += 4) {
            int jj = j2 + q;                         // may exceed m-1: w=0
            int s   = __shfl(sj, jj);
            float w = __shfl(exv, jj);
            uint4 raw = *(const uint4*)(gb + (size_t)s * 128 + ql * 8);
            float2 p0 = bfpair(raw.x), p1 = bfpair(raw.y);
            float2 p2 = bfpair(raw.z), p3 = bfpair(raw.w);
            acc2[0].x += w * p0.x; acc2[0].y += w * p0.y;
            acc2[1].x += w * p1.x; acc2[1].y += w * p1.y;
            acc2[2].x += w * p2.x; acc2[2].y += w * p2.y;
            acc2[3].x += w * p3.x; acc2[3].y += w * p3.y;
        }
    }
    #pragma unroll
    for (int k = 0; k < 4; k++) {
        acc2[k].x += __shfl_down(acc2[k].x, 32);
        acc2[k].y += __shfl_down(acc2[k].y, 32);
        acc2[k].x += __shfl_down(acc2[k].x, 16);
        acc2[k].y += __shfl_down(acc2[k].y, 16);
    }
    #pragma unroll
    for (int off = 32; off; off >>= 1) den += __shfl_xor(den, off);
    if (lane < 16) {
        float inv = 1.f / (den + 1e-16f);
        float4 o0, o1;
        o0.x = acc2[0].x * inv + b2[ql * 8 + 0];
        o0.y = acc2[0].y * inv + b2[ql * 8 + 1];
        o0.z = acc2[1].x * inv + b2[ql * 8 + 2];
        o0.w = acc2[1].y * inv + b2[ql * 8 + 3];
        o1.x = acc2[2].x * inv + b2[ql * 8 + 4];
        o1.y = acc2[2].y * inv + b2[ql * 8 + 5];
        o1.z = acc2[3].x * inv + b2[ql * 8 + 6];
        o1.w = acc2[3].y * inv + b2[ql * 8 + 7];
        *(float4*)(outp + (size_t)node * 128 + ql * 8)     = o0;
        *(float4*)(outp + (size_t)node * 128 + ql * 8 + 4) = o1;
    }
}

extern "C" void kernel_launch(void* const* d_in, const int* in_sizes, int n_in,
                              void* d_out, int out_size, void* d_ws, size_t ws_size,
                              hipStream_t stream) {
    const float* x     = (const float*)d_in[0];
    const int*   ei    = (const int*)d_in[1];      // int32 on device
    const float* eattr = (const float*)d_in[2];
    const float* W1    = (const float*)d_in[3];
    const float* We1   = (const float*)d_in[4];
    const float* as1   = (const float*)d_in[5];
    const float* ad1   = (const float*)d_in[6];
    const float* ae1   = (const float*)d_in[7];
    const float* b1    = (const float*)d_in[8];
    const float* W2    = (const float*)d_in[9];
    const float* We2   = (const float*)d_in[10];
    const float* as2   = (const float*)d_in[11];
    const float* ad2   = (const float*)d_in[12];
    const float* ae2   = (const float*)d_in[13];
    const float* b2    = (const float*)d_in[14];
    float* out = (float*)d_out;

    // ---- workspace carve ----
    int* idg    = (int*)d_ws;                      // NN
    int* cnt    = idg + NN;                        // NN
    int* rowptr = cnt + NN;                        // NN+16
    int* bsum   = rowptr + NN + 16;                // 32
    int* boff   = bsum + 32;                       // 32
    int2* slot  = (int2*)(boff + 32);              // EP (8B-aligned)
    float* asrc1 = (float*)(slot + EP);            // 4*NN
    float* adst1 = asrc1 + 4 * NN;                 // 4*NN
    float* asrc2 = adst1 + 4 * NN;                 // NN
    float* adst2 = asrc2 + NN;                     // NN
    float* vbuf  = adst2 + NN;                     // 64
    unsigned short* ub = (unsigned short*)(((uintptr_t)(vbuf + 64) + 63) & ~(uintptr_t)63);
    unsigned short* x_bf  = ub;                      // NN*128
    unsigned short* W1t   = x_bf + (size_t)NN * 128; // 256*128
    unsigned short* W2t   = W1t + 32768;             // 128*256
    unsigned short* h1_bf = W2t + 32768;             // NN*256
    unsigned short* h2_bf = h1_bf + (size_t)NN * 256;// NN*256
    unsigned short* g2_bf = h2_bf + (size_t)NN * 256;// NN*128

    hipMemsetAsync(idg, 0, (size_t)2 * NN * sizeof(int), stream);

    // prep (v, Wt casts, degree hist, x cast) + CSR build
    k_prep<<<9632, 256, 0, stream>>>(We1, ae1, We2, ae2, vbuf, W1, W1t, W2, W2t,
                                     ei, idg, x, x_bf);
    k_scan1<<<NB, 512, 0, stream>>>(idg, rowptr, bsum);
    k_scan2<<<1, 64, 0, stream>>>(bsum, boff, rowptr);
    k_scan3<<<NB, 512, 0, stream>>>(rowptr, boff);
    k_scatter<<<(EE + 255) / 256, 256, 0, stream>>>(ei, eattr, rowptr, cnt, slot);
    k_selfattr<<<(NN + 255) / 256, 256, 0, stream>>>(rowptr, slot);

    // ---- layer 1 ----  (gemm with fused attn scalars)
    gemm_mfma<128, 4, 4><<<dim3(4, (NN + 127) / 128), 256, 0, stream>>>(
        x_bf, W1t, h1_bf, as1, ad1, asrc1, adst1, NN, 256);
    k_agg1<<<(NN + 3) / 4, 256, 0, stream>>>(rowptr, slot, asrc1, adst1, vbuf,
                                             h1_bf, b1, h2_bf);

    // ---- layer 2 ----
    gemm_mfma<256, 8, 1><<<dim3(1, (NN + 127) / 128), 256, 0, stream>>>(
        h2_bf, W2t, g2_bf, as2, ad2, asrc2, adst2, NN, 128);
    k_agg2<<<(NN + 3) / 4, 256, 0, stream>>>(rowptr, slot, asrc2, adst2, vbuf + 8,
                                             g2_bf, b2, out);
}

// Round 9
// 333.879 us; speedup vs baseline: 1.4068x; 1.0656x over previous
//
#include <hip/hip_runtime.h>
#include <hip/hip_bf16.h>

#define NN 50000
#define EE 800000
#define SCAN_B 2048
#define NB ((NN + SCAN_B - 1) / SCAN_B)   // 25 scan blocks

// NOTE: harness materializes integer inputs as int32 -> edge_index is const int*.
// NOTE (r7): fp32 scatter atomics = ~80us atomic-latency wall. Avoided.
// NOTE (r9): CSR holds real edges only; self-loop handled inline in agg kernels.
//            rank[] from hist's atomicAdd return -> scatter is atomic-free.

typedef short bf16x8 __attribute__((ext_vector_type(8)));
typedef float f32x4  __attribute__((ext_vector_type(4)));

__device__ __forceinline__ float bf2f(unsigned short u) {
    return __uint_as_float(((unsigned)u) << 16);
}
__device__ __forceinline__ unsigned short f2bf(float f) {
    unsigned b = __float_as_uint(f);
    b += 0x7fffu + ((b >> 16) & 1u);           // RNE
    return (unsigned short)(b >> 16);
}
// dword holding two bf16 -> two floats (1 shl + 1 and)
__device__ __forceinline__ float2 bfpair(unsigned u) {
    return make_float2(__uint_as_float(u << 16), __uint_as_float(u & 0xffff0000u));
}

// ---------------- fused prep: v-projection + Wt casts + hist/rank + x cast ----
// block 0: v ; blocks [1,256]: Wt ; [257,3381]: hist+rank ; [3382,9631]: castx
__global__ void k_prep(const float* __restrict__ We1, const float* __restrict__ ae1,
                       const float* __restrict__ We2, const float* __restrict__ ae2,
                       float* __restrict__ v,
                       const float* __restrict__ W1, unsigned short* __restrict__ W1t,
                       const float* __restrict__ W2, unsigned short* __restrict__ W2t,
                       const int* __restrict__ ei, int* __restrict__ idg,
                       int* __restrict__ rank,
                       const float* __restrict__ x, unsigned short* __restrict__ xb) {
    int bid = blockIdx.x, t = threadIdx.x;
    if (bid == 0) {
        if (t < 8) {            // layer1: c=t>>2, h=t&3 -> v[c*4+h]
            int c = t >> 2, h = t & 3;
            float s = 0.f;
            for (int d = 0; d < 64; d++) s += We1[c * 256 + h * 64 + d] * ae1[h * 64 + d];
            v[c * 4 + h] = s;
        } else if (t < 10) {    // layer2: c=t-8 -> v[8+c]
            int c = t - 8;
            float s = 0.f;
            for (int d = 0; d < 128; d++) s += We2[c * 128 + d] * ae2[d];
            v[8 + c] = s;
        }
    } else if (bid <= 256) {
        int idx = (bid - 1) * 256 + t;
        if (idx < 32768) {                 // W1: 128x256 -> 256x128
            int k = idx >> 8, n = idx & 255;
            W1t[n * 128 + k] = f2bf(W1[idx]);
        } else {                           // W2: 256x128 -> 128x256
            int i = idx - 32768;
            int k = i >> 7, n = i & 127;
            W2t[n * 256 + k] = f2bf(W2[i]);
        }
    } else if (bid <= 256 + 3125) {
        int e = (bid - 257) * 256 + t;
        if (e < EE) rank[e] = atomicAdd(&idg[ei[EE + e]], 1);
    } else {
        int i = (bid - 3382) * 256 + t;
        if (i < NN * 128 / 4) {
            float4 vv = ((const float4*)x)[i];
            ushort4 o;
            o.x = f2bf(vv.x); o.y = f2bf(vv.y); o.z = f2bf(vv.z); o.w = f2bf(vv.w);
            ((ushort4*)xb)[i] = o;
        }
    }
}

// ---------------- CSR build: 3-pass exclusive scan of idg -> rowptr -----------
__global__ void k_scan1(const int* __restrict__ idg, int* __restrict__ rowptr,
                        int* __restrict__ bsum) {
    __shared__ int sh[512];
    int t = threadIdx.x;
    int base = blockIdx.x * SCAN_B + t * 4;
    int v[4]; int s = 0;
    #pragma unroll
    for (int j = 0; j < 4; j++) {
        int i = base + j;
        v[j] = (i < NN) ? idg[i] : 0;
        s += v[j];
    }
    sh[t] = s;
    __syncthreads();
    for (int off = 1; off < 512; off <<= 1) {
        int a = (t >= off) ? sh[t - off] : 0;
        __syncthreads();
        sh[t] += a;
        __syncthreads();
    }
    int run = sh[t] - s;
    #pragma unroll
    for (int j = 0; j < 4; j++) {
        int i = base + j;
        if (i < NN) rowptr[i] = run;
        run += v[j];
    }
    if (t == 511) bsum[blockIdx.x] = sh[511];
}

__global__ void k_scan2(const int* __restrict__ bsum, int* __restrict__ boff,
                        int* __restrict__ rowptr) {
    if (threadIdx.x == 0) {
        int acc = 0;
        for (int b = 0; b < NB; b++) { boff[b] = acc; acc += bsum[b]; }
        rowptr[NN] = acc;      // == EE
    }
}

__global__ void k_scan3(int* __restrict__ rowptr, const int* __restrict__ boff) {
    int t = threadIdx.x;
    int i = blockIdx.x * SCAN_B + t * 4;
    int off = boff[blockIdx.x];
    #pragma unroll
    for (int j = 0; j < 4; j++)
        if (i + j < NN) rowptr[i + j] += off;
}

// ---------------- atomic-free scatter: p = rowptr[dst] + rank[e] --------------
__global__ void k_scatter(const int* __restrict__ ei, const float* __restrict__ eattr,
                          const int* __restrict__ rowptr, const int* __restrict__ rank,
                          int2* __restrict__ slot) {
    int e = blockIdx.x * blockDim.x + threadIdx.x;
    if (e >= EE) return;
    int s = ei[e], d = ei[EE + e];
    int p = rowptr[d] + rank[e];
    float2 a = ((const float2*)eattr)[e];
    unsigned a0 = f2bf(a.x), a1 = f2bf(a.y);
    slot[p] = make_int2(s, (int)(a0 | (a1 << 16)));
}

// ---------------- MFMA bf16 GEMM with fused attention-scalar epilogue ---------
// C[M,N] = A[M,K] @ Bt[N,K]^T (bf16 out). Per block: 128 rows x NT*16 cols.
template <int K, int NT, int H>
__global__ __launch_bounds__(256) void gemm_mfma(const unsigned short* __restrict__ A,
                                                 const unsigned short* __restrict__ Bt,
                                                 unsigned short* __restrict__ C,
                                                 const float* __restrict__ avs,
                                                 const float* __restrict__ avd,
                                                 float* __restrict__ asrc,
                                                 float* __restrict__ adst,
                                                 int M, int N) {
    int wave = threadIdx.x >> 6, lane = threadIdx.x & 63;
    int l16 = lane & 15, quad = lane >> 4;
    int m0 = blockIdx.y * 128 + wave * 32;
    int n0 = blockIdx.x * (NT * 16);

    f32x4 acc[2][NT];
    #pragma unroll
    for (int mt = 0; mt < 2; mt++)
        #pragma unroll
        for (int nt = 0; nt < NT; nt++)
            acc[mt][nt] = (f32x4){0.f, 0.f, 0.f, 0.f};

    int ar0 = min(m0 + l16, M - 1);
    int ar1 = min(m0 + 16 + l16, M - 1);
    const unsigned short* a0 = A + (size_t)ar0 * K + quad * 8;
    const unsigned short* a1 = A + (size_t)ar1 * K + quad * 8;
    const unsigned short* bp = Bt + (size_t)(n0 + l16) * K + quad * 8;

    #pragma unroll
    for (int k0 = 0; k0 < K; k0 += 32) {
        bf16x8 af0 = *(const bf16x8*)(a0 + k0);
        bf16x8 af1 = *(const bf16x8*)(a1 + k0);
        #pragma unroll
        for (int nt = 0; nt < NT; nt++) {
            bf16x8 bf = *(const bf16x8*)(bp + (size_t)nt * 16 * K + k0);
            acc[0][nt] = __builtin_amdgcn_mfma_f32_16x16x32_bf16(af0, bf, acc[0][nt], 0, 0, 0);
            acc[1][nt] = __builtin_amdgcn_mfma_f32_16x16x32_bf16(af1, bf, acc[1][nt], 0, 0, 0);
        }
    }

    // C store. C/D layout: col = l16, row = quad*4 + reg
    #pragma unroll
    for (int mt = 0; mt < 2; mt++)
        #pragma unroll
        for (int reg = 0; reg < 4; reg++) {
            int row = m0 + mt * 16 + quad * 4 + reg;
            if (row < M) {
                #pragma unroll
                for (int nt = 0; nt < NT; nt++)
                    C[(size_t)row * N + n0 + nt * 16 + l16] = f2bf(acc[mt][nt][reg]);
            }
        }

    // fused attn scalars: asrc/adst[row, head] from fp32 acc
    float ws[NT], wd[NT];
    #pragma unroll
    for (int nt = 0; nt < NT; nt++) {
        ws[nt] = avs[n0 + nt * 16 + l16];
        wd[nt] = avd[n0 + nt * 16 + l16];
    }
    int hh = n0 >> 6;          // head index (layer1: blockIdx.x; layer2: 0)
    #pragma unroll
    for (int mt = 0; mt < 2; mt++)
        #pragma unroll
        for (int reg = 0; reg < 4; reg++) {
            int row = m0 + mt * 16 + quad * 4 + reg;
            float s1 = 0.f, s2 = 0.f;
            #pragma unroll
            for (int nt = 0; nt < NT; nt++) {
                float c = acc[mt][nt][reg];
                s1 += c * ws[nt];
                s2 += c * wd[nt];
            }
            #pragma unroll
            for (int off = 1; off < 16; off <<= 1) {
                s1 += __shfl_xor(s1, off);
                s2 += __shfl_xor(s2, off);
            }
            if (l16 == 0 && row < M) {
                asrc[row * H + hh] = s1;
                adst[row * H + hh] = s2;
            }
        }
}

// ---------------- layer1 fused softmax+aggregate+bias+ELU ---------------------
// one wave / node; software-pipelined alpha prefetch (batch k+1 slot/asrc loads
// issued before batch k gathers); self-loop handled inline (mean attrs from the
// prefetch-accumulated sums, coalesced h[node] gather).
__global__ __launch_bounds__(256) void k_agg1(const int* __restrict__ rowptr,
                       const int2* __restrict__ slot, const float* __restrict__ asrc,
                       const float* __restrict__ adst, const float* __restrict__ v,
                       const unsigned short* __restrict__ hb, const float* __restrict__ b1,
                       unsigned short* __restrict__ h2b) {
    int node = blockIdx.x * 4 + (threadIdx.x >> 6);
    if (node >= NN) return;
    int lane = threadIdx.x & 63;
    int j    = lane & 15;        // prefetch: edge within batch
    int hp   = lane >> 4;        // prefetch: head
    int half = lane >> 5;        // gather: which edge of the pair
    int hl   = lane & 31;        // gather: channel-lane (8 ch each)
    int hh2  = hl >> 3;          // head owning this lane's channels
    int beg = rowptr[node], end = rowptr[node + 1];
    float ad_p = adst[node * 4 + hp];
    float v0 = v[hp], v1 = v[4 + hp];
    float2 acc2[4] = {};
    float den = 0.f, s0 = 0.f, s1 = 0.f;

    // preload first batch
    int pb = beg;
    int m = min(16, end - pb);
    int sj = 0; float aa0 = 0.f, aa1 = 0.f, av = 0.f;
    if (j < m) {
        int2 sl = slot[pb + j];
        sj = sl.x;
        float2 a = bfpair((unsigned)sl.y);
        aa0 = a.x; aa1 = a.y;
        av = asrc[sj * 4 + hp];
    }
    while (pb < end) {
        int cm = m, csj = sj;
        float ca0 = aa0, ca1 = aa1, cav = av;
        pb += 16;
        // issue next batch's loads
        m = min(16, end - pb);
        sj = 0; aa0 = 0.f; aa1 = 0.f; av = 0.f;
        if (j < m) {
            int2 sl = slot[pb + j];
            sj = sl.x;
            float2 a = bfpair((unsigned)sl.y);
            aa0 = a.x; aa1 = a.y;
            av = asrc[sj * 4 + hp];
        }
        // alpha/exp for current batch
        float exv = 0.f;
        if (j < cm) {
            s0 += ca0; s1 += ca1;
            float al = cav + ad_p + ca0 * v0 + ca1 * v1;
            al = (al > 0.f) ? al : 0.2f * al;
            exv = __expf(al);
        }
        den += exv;
        // gathers for current batch: half-wave per edge, 16B/lane
        #pragma unroll 2
        for (int j2 = 0; j2 < cm; j2 += 2) {
            int jj = j2 + half;                      // may hit cm (odd cm): w=0
            int s   = __shfl(csj, jj);
            float w = __shfl(exv, jj + (hh2 << 4));
            uint4 raw = *(const uint4*)(hb + (size_t)s * 256 + hl * 8);
            float2 p0 = bfpair(raw.x), p1 = bfpair(raw.y);
            float2 p2 = bfpair(raw.z), p3 = bfpair(raw.w);
            acc2[0].x += w * p0.x; acc2[0].y += w * p0.y;
            acc2[1].x += w * p1.x; acc2[1].y += w * p1.y;
            acc2[2].x += w * p2.x; acc2[2].y += w * p2.y;
            acc2[3].x += w * p3.x; acc2[3].y += w * p3.y;
        }
    }
    // self-loop: mean attrs over real edges (0 if none), alpha, gather h[node]
    #pragma unroll
    for (int off = 1; off < 16; off <<= 1) {
        s0 += __shfl_xor(s0, off);
        s1 += __shfl_xor(s1, off);
    }
    float dg = fmaxf((float)(end - beg), 1.0f);
    float als = asrc[node * 4 + hp] + ad_p + (s0 / dg) * v0 + (s1 / dg) * v1;
    als = (als > 0.f) ? als : 0.2f * als;
    float exs = __expf(als);
    #pragma unroll
    for (int off = 8; off; off >>= 1) den += __shfl_xor(den, off);
    den += exs;
    float den_h  = __shfl(den, hh2 << 4);
    float w_self = __shfl(exs, hh2 << 4);
    if (half == 0) {
        uint4 raw = *(const uint4*)(hb + (size_t)node * 256 + hl * 8);
        float2 p0 = bfpair(raw.x), p1 = bfpair(raw.y);
        float2 p2 = bfpair(raw.z), p3 = bfpair(raw.w);
        acc2[0].x += w_self * p0.x; acc2[0].y += w_self * p0.y;
        acc2[1].x += w_self * p1.x; acc2[1].y += w_self * p1.y;
        acc2[2].x += w_self * p2.x; acc2[2].y += w_self * p2.y;
        acc2[3].x += w_self * p3.x; acc2[3].y += w_self * p3.y;
    }
    #pragma unroll
    for (int k = 0; k < 4; k++) {
        acc2[k].x += __shfl_down(acc2[k].x, 32);
        acc2[k].y += __shfl_down(acc2[k].y, 32);
    }
    if (lane < 32) {
        float inv = 1.f / (den_h + 1e-16f);
        short ov[8];
        #pragma unroll
        for (int k = 0; k < 4; k++) {
            float va = acc2[k].x * inv + b1[hl * 8 + 2 * k];
            float vb = acc2[k].y * inv + b1[hl * 8 + 2 * k + 1];
            va = (va > 0.f) ? va : __expf(va) - 1.f;
            vb = (vb > 0.f) ? vb : __expf(vb) - 1.f;
            ov[2 * k]     = (short)f2bf(va);
            ov[2 * k + 1] = (short)f2bf(vb);
        }
        bf16x8 o = {ov[0], ov[1], ov[2], ov[3], ov[4], ov[5], ov[6], ov[7]};
        *(bf16x8*)(h2b + (size_t)node * 256 + hl * 8) = o;
    }
}

// ---------------- layer2 fused softmax+aggregate+bias (H=1, 128ch, fp32 out) --
__global__ __launch_bounds__(256) void k_agg2(const int* __restrict__ rowptr,
                       const int2* __restrict__ slot, const float* __restrict__ asrc,
                       const float* __restrict__ adst, const float* __restrict__ v,
                       const unsigned short* __restrict__ gb, const float* __restrict__ b2,
                       float* __restrict__ outp) {
    int node = blockIdx.x * 4 + (threadIdx.x >> 6);
    if (node >= NN) return;
    int lane = threadIdx.x & 63;
    int q  = lane >> 4;          // gather: which edge of the quad
    int ql = lane & 15;          // gather: channel-lane (8 ch each)
    int beg = rowptr[node], end = rowptr[node + 1];
    float ad = adst[node];
    float v0 = v[0], v1 = v[1];
    float2 acc2[4] = {};
    float den = 0.f, s0 = 0.f, s1 = 0.f;
    for (int pb = beg; pb < end; pb += 64) {
        int m = min(64, end - pb);
        int sj = 0; float exv = 0.f;
        if (lane < m) {
            int2 sl = slot[pb + lane];
            sj = sl.x;
            float2 a = bfpair((unsigned)sl.y);
            s0 += a.x; s1 += a.y;
            float al = asrc[sj] + ad + a.x * v0 + a.y * v1;
            al = (al > 0.f) ? al : 0.2f * al;
            exv = __expf(al);
        }
        den += exv;
        #pragma unroll 2
        for (int j2 = 0; j2 < m; j2 += 4) {
            int jj = j2 + q;                         // may exceed m-1: w=0
            int s   = __shfl(sj, jj);
            float w = __shfl(exv, jj);
            uint4 raw = *(const uint4*)(gb + (size_t)s * 128 + ql * 8);
            float2 p0 = bfpair(raw.x), p1 = bfpair(raw.y);
            float2 p2 = bfpair(raw.z), p3 = bfpair(raw.w);
            acc2[0].x += w * p0.x; acc2[0].y += w * p0.y;
            acc2[1].x += w * p1.x; acc2[1].y += w * p1.y;
            acc2[2].x += w * p2.x; acc2[2].y += w * p2.y;
            acc2[3].x += w * p3.x; acc2[3].y += w * p3.y;
        }
    }
    // self-loop epilogue
    #pragma unroll
    for (int off = 32; off; off >>= 1) {
        s0  += __shfl_xor(s0, off);
        s1  += __shfl_xor(s1, off);
        den += __shfl_xor(den, off);
    }
    float dg = fmaxf((float)(end - beg), 1.0f);
    float als = asrc[node] + ad + (s0 / dg) * v0 + (s1 / dg) * v1;
    als = (als > 0.f) ? als : 0.2f * als;
    float exs = __expf(als);
    den += exs;
    if (q == 0) {
        uint4 raw = *(const uint4*)(gb + (size_t)node * 128 + ql * 8);
        float2 p0 = bfpair(raw.x), p1 = bfpair(raw.y);
        float2 p2 = bfpair(raw.z), p3 = bfpair(raw.w);
        acc2[0].x += exs * p0.x; acc2[0].y += exs * p0.y;
        acc2[1].x += exs * p1.x; acc2[1].y += exs * p1.y;
        acc2[2].x += exs * p2.x; acc2[2].y += exs * p2.y;
        acc2[3].x += exs * p3.x; acc2[3].y += exs * p3.y;
    }
    #pragma unroll
    for (int k = 0; k < 4; k++) {
        acc2[k].x += __shfl_down(acc2[k].x, 32);
        acc2[k].y += __shfl_down(acc2[k].y, 32);
        acc2[k].x += __shfl_down(acc2[k].x, 16);
        acc2[k].y += __shfl_down(acc2[k].y, 16);
    }
    if (lane < 16) {
        float inv = 1.f / (den + 1e-16f);
        float4 o0, o1;
        o0.x = acc2[0].x * inv + b2[ql * 8 + 0];
        o0.y = acc2[0].y * inv + b2[ql * 8 + 1];
        o0.z = acc2[1].x * inv + b2[ql * 8 + 2];
        o0.w = acc2[1].y * inv + b2[ql * 8 + 3];
        o1.x = acc2[2].x * inv + b2[ql * 8 + 4];
        o1.y = acc2[2].y * inv + b2[ql * 8 + 5];
        o1.z = acc2[3].x * inv + b2[ql * 8 + 6];
        o1.w = acc2[3].y * inv + b2[ql * 8 + 7];
        *(float4*)(outp + (size_t)node * 128 + ql * 8)     = o0;
        *(float4*)(outp + (size_t)node * 128 + ql * 8 + 4) = o1;
    }
}

extern "C" void kernel_launch(void* const* d_in, const int* in_sizes, int n_in,
                              void* d_out, int out_size, void* d_ws, size_t ws_size,
                              hipStream_t stream) {
    const float* x     = (const float*)d_in[0];
    const int*   ei    = (const int*)d_in[1];      // int32 on device
    const float* eattr = (const float*)d_in[2];
    const float* W1    = (const float*)d_in[3];
    const float* We1   = (const float*)d_in[4];
    const float* as1   = (const float*)d_in[5];
    const float* ad1   = (const float*)d_in[6];
    const float* ae1   = (const float*)d_in[7];
    const float* b1    = (const float*)d_in[8];
    const float* W2    = (const float*)d_in[9];
    const float* We2   = (const float*)d_in[10];
    const float* as2   = (const float*)d_in[11];
    const float* ad2   = (const float*)d_in[12];
    const float* ae2   = (const float*)d_in[13];
    const float* b2    = (const float*)d_in[14];
    float* out = (float*)d_out;

    // ---- workspace carve ----
    int* idg    = (int*)d_ws;                      // NN
    int* rank   = idg + NN;                        // EE
    int* rowptr = rank + EE;                       // NN+16
    int* bsum   = rowptr + NN + 16;                // 32
    int* boff   = bsum + 32;                       // 32
    int2* slot  = (int2*)(boff + 32);              // EE (8B-aligned)
    float* asrc1 = (float*)(slot + EE);            // 4*NN
    float* adst1 = asrc1 + 4 * NN;                 // 4*NN
    float* asrc2 = adst1 + 4 * NN;                 // NN
    float* adst2 = asrc2 + NN;                     // NN
    float* vbuf  = adst2 + NN;                     // 64
    unsigned short* ub = (unsigned short*)(((uintptr_t)(vbuf + 64) + 63) & ~(uintptr_t)63);
    unsigned short* x_bf  = ub;                      // NN*128
    unsigned short* W1t   = x_bf + (size_t)NN * 128; // 256*128
    unsigned short* W2t   = W1t + 32768;             // 128*256
    unsigned short* h1_bf = W2t + 32768;             // NN*256
    unsigned short* h2_bf = h1_bf + (size_t)NN * 256;// NN*256
    unsigned short* g2_bf = h2_bf + (size_t)NN * 256;// NN*128

    hipMemsetAsync(idg, 0, (size_t)NN * sizeof(int), stream);

    // prep (v, Wt casts, degree hist + rank, x cast) + CSR build (atomic-free)
    k_prep<<<9632, 256, 0, stream>>>(We1, ae1, We2, ae2, vbuf, W1, W1t, W2, W2t,
                                     ei, idg, rank, x, x_bf);
    k_scan1<<<NB, 512, 0, stream>>>(idg, rowptr, bsum);
    k_scan2<<<1, 64, 0, stream>>>(bsum, boff, rowptr);
    k_scan3<<<NB, 512, 0, stream>>>(rowptr, boff);
    k_scatter<<<(EE + 255) / 256, 256, 0, stream>>>(ei, eattr, rowptr, rank, slot);

    // ---- layer 1 ----  (gemm with fused attn scalars)
    gemm_mfma<128, 4, 4><<<dim3(4, (NN + 127) / 128), 256, 0, stream>>>(
        x_bf, W1t, h1_bf, as1, ad1, asrc1, adst1, NN, 256);
    k_agg1<<<(NN + 3) / 4, 256, 0, stream>>>(rowptr, slot, asrc1, adst1, vbuf,
                                             h1_bf, b1, h2_bf);

    // ---- layer 2 ----
    gemm_mfma<256, 8, 1><<<dim3(1, (NN + 127) / 128), 256, 0, stream>>>(
        h2_bf, W2t, g2_bf, as2, ad2, asrc2, adst2, NN, 128);
    k_agg2<<<(NN + 3) / 4, 256, 0, stream>>>(rowptr, slot, asrc2, adst2, vbuf + 8,
                                             g2_bf, b2, out);
}